// Round 5
// baseline (1096.678 us; speedup 1.0000x reference)
//
#include <hip/hip_runtime.h>
#include <stdint.h>

#define B_ 2
#define T_ 2048
#define C_ 2048
#define F_ 8192
#define M_ 4096   // B_*T_

typedef __attribute__((ext_vector_type(8))) __bf16 bf16x8;
typedef __attribute__((ext_vector_type(4))) float f32x4;

__device__ __forceinline__ unsigned short f2bf(float f) {
  union { float f; unsigned u; } v; v.f = f;
  unsigned r = v.u + 0x7fffu + ((v.u >> 16) & 1u);
  return (unsigned short)(r >> 16);
}
__device__ __forceinline__ float b2f(unsigned short h) {
  union { unsigned u; float f; } v; v.u = ((unsigned)h) << 16; return v.f;
}

__device__ __forceinline__ void gload16(const void* g, void* l) {
  __builtin_amdgcn_global_load_lds((__attribute__((address_space(1))) void*)g,
                                   (__attribute__((address_space(3))) void*)l,
                                   16, 0, 0);
}

// ---------- transpose + f32->bf16: WT[n][k] = W[k][n] ----------
__global__ __launch_bounds__(256) void k_transpose_cast(
    const float* __restrict__ W, unsigned short* __restrict__ WT, int K, int N) {
  __shared__ unsigned short tile[32][33];
  const int n0 = blockIdx.x * 32, k0 = blockIdx.y * 32;
  const int tx = threadIdx.x & 31, ty = threadIdx.x >> 5;
#pragma unroll
  for (int i = 0; i < 4; ++i)
    tile[ty + 8 * i][tx] = f2bf(W[(size_t)(k0 + ty + 8 * i) * N + n0 + tx]);
  __syncthreads();
#pragma unroll
  for (int i = 0; i < 4; ++i)
    WT[(size_t)(n0 + ty + 8 * i) * K + k0 + tx] = tile[tx][ty + 8 * i];
}

// ---------- LayerNorm over C=2048 (f32 in, bf16 out + f32 last-row out) ----------
__global__ __launch_bounds__(256) void k_layernorm(
    const float* __restrict__ x, const float* __restrict__ g,
    const float* __restrict__ beta, unsigned short* __restrict__ y,
    float* __restrict__ last_out) {
  const int row = blockIdx.x;
  const int t = row & (T_ - 1);
  const int bi = row >> 11;
  const float* xr = x + (size_t)row * C_;
  const int base = threadIdx.x * 8;
  float lv[8];
  {
    float4 a = *(const float4*)(xr + base);
    float4 b = *(const float4*)(xr + base + 4);
    lv[0]=a.x; lv[1]=a.y; lv[2]=a.z; lv[3]=a.w; lv[4]=b.x; lv[5]=b.y; lv[6]=b.z; lv[7]=b.w;
  }
  float s = 0.f, q = 0.f;
#pragma unroll
  for (int j = 0; j < 8; ++j) { s += lv[j]; q += lv[j] * lv[j]; }
#pragma unroll
  for (int o = 32; o > 0; o >>= 1) { s += __shfl_down(s, o); q += __shfl_down(q, o); }
  __shared__ float rs[4], rq[4];
  if ((threadIdx.x & 63) == 0) { rs[threadIdx.x >> 6] = s; rq[threadIdx.x >> 6] = q; }
  __syncthreads();
  s = rs[0] + rs[1] + rs[2] + rs[3];
  q = rq[0] + rq[1] + rq[2] + rq[3];
  const float mean = s * (1.f / C_);
  const float var = q * (1.f / C_) - mean * mean;
  const float inv = 1.f / sqrtf(var + 1e-5f);
  float ov[8];
  unsigned short o8[8];
#pragma unroll
  for (int j = 0; j < 8; ++j) {
    ov[j] = (lv[j] - mean) * inv * g[base + j] + beta[base + j];
    o8[j] = f2bf(ov[j]);
  }
  *(uint4*)(y + (size_t)row * C_ + base) = *(uint4*)o8;
  if (last_out != nullptr && t == T_ - 1) {
    float* lp = last_out + (size_t)bi * C_ + base;
    *(float4*)lp = make_float4(ov[0], ov[1], ov[2], ov[3]);
    *(float4*)(lp + 4) = make_float4(ov[4], ov[5], ov[6], ov[7]);
  }
}

// ---------- token-shift mix (attention: 3 outputs), bf16 in/out ----------
__global__ __launch_bounds__(256) void k_mix3(
    const unsigned short* __restrict__ x1, const float* __restrict__ shift,
    const float* __restrict__ tmk, const float* __restrict__ tmv,
    const float* __restrict__ tmr,
    unsigned short* __restrict__ xk, unsigned short* __restrict__ xv,
    unsigned short* __restrict__ xr) {
  const int row = blockIdx.x;
  const int t = row & (T_ - 1);
  const int bi = row >> 11;
  const int c0 = threadIdx.x * 8;
  const size_t o = (size_t)row * C_ + c0;
  unsigned short cur8[8];
  *(uint4*)cur8 = *(const uint4*)(x1 + o);
  float pv[8];
  if (t == 0) {
    const float* sp = shift + (size_t)bi * C_ + c0;
#pragma unroll
    for (int j = 0; j < 8; ++j) pv[j] = sp[j];
  } else {
    unsigned short p8[8];
    *(uint4*)p8 = *(const uint4*)(x1 + o - C_);
#pragma unroll
    for (int j = 0; j < 8; ++j) pv[j] = b2f(p8[j]);
  }
  unsigned short ok[8], ov[8], orr[8];
#pragma unroll
  for (int j = 0; j < 8; ++j) {
    const float a = b2f(cur8[j]), p = pv[j];
    const float mk = tmk[c0 + j], mv = tmv[c0 + j], mr = tmr[c0 + j];
    ok[j]  = f2bf(a * mk + p * (1.f - mk));
    ov[j]  = f2bf(a * mv + p * (1.f - mv));
    orr[j] = f2bf(a * mr + p * (1.f - mr));
  }
  *(uint4*)(xk + o) = *(uint4*)ok;
  *(uint4*)(xv + o) = *(uint4*)ov;
  *(uint4*)(xr + o) = *(uint4*)orr;
}

// ---------- token-shift mix (ffn: 2 outputs) ----------
__global__ __launch_bounds__(256) void k_mix2(
    const unsigned short* __restrict__ x2, const float* __restrict__ shift,
    const float* __restrict__ fmk, const float* __restrict__ fmr,
    unsigned short* __restrict__ xk2, unsigned short* __restrict__ xr2) {
  const int row = blockIdx.x;
  const int t = row & (T_ - 1);
  const int bi = row >> 11;
  const int c0 = threadIdx.x * 8;
  const size_t o = (size_t)row * C_ + c0;
  unsigned short cur8[8];
  *(uint4*)cur8 = *(const uint4*)(x2 + o);
  float pv[8];
  if (t == 0) {
    const float* sp = shift + (size_t)bi * C_ + c0;
#pragma unroll
    for (int j = 0; j < 8; ++j) pv[j] = sp[j];
  } else {
    unsigned short p8[8];
    *(uint4*)p8 = *(const uint4*)(x2 + o - C_);
#pragma unroll
    for (int j = 0; j < 8; ++j) pv[j] = b2f(p8[j]);
  }
  unsigned short ok[8], orr[8];
#pragma unroll
  for (int j = 0; j < 8; ++j) {
    const float a = b2f(cur8[j]), p = pv[j];
    const float mk = fmk[c0 + j], mr = fmr[c0 + j];
    ok[j]  = f2bf(a * mk + p * (1.f - mk));
    orr[j] = f2bf(a * mr + p * (1.f - mr));
  }
  *(uint4*)(xk2 + o) = *(uint4*)ok;
  *(uint4*)(xr2 + o) = *(uint4*)orr;
}

// ---------- WKV serial scan, one thread per (b,c) channel; f32 state out ----------
#define WKV_STEP(KT, VT, TIDX)                                        \
  {                                                                   \
    const float kt = (KT), vt = (VT);                                 \
    const float ww = u + kt;                                          \
    const float p = fmaxf(pp, ww);                                    \
    const float e1 = expf(pp - p), e2 = expf(ww - p);                 \
    yp[(size_t)(TIDX) * C_] = (e1 * aa + e2 * vt) / (e1 * bbv + e2);  \
    const float ww2 = pp + w;                                         \
    const float p2 = fmaxf(ww2, kt);                                  \
    const float e1b = expf(ww2 - p2), e2b = expf(kt - p2);            \
    aa = e1b * aa + e2b * vt;                                         \
    bbv = e1b * bbv + e2b;                                            \
    pp = p2;                                                          \
  }

__global__ __launch_bounds__(256) void k_wkv(
    const float* __restrict__ kk, const float* __restrict__ vv,
    const float* __restrict__ td, const float* __restrict__ tf,
    const float* __restrict__ st, float* __restrict__ y,
    float* __restrict__ out_state) {
  const int gid = blockIdx.x * 256 + threadIdx.x;
  const int bi = gid >> 11;
  const int c = gid & (C_ - 1);
  const float w = -expf(td[c]);
  const float u = tf[c];
  const float* sb = st + (size_t)bi * 3 * C_;
  float aa = sb[c], bbv = sb[C_ + c], pp = sb[2 * C_ + c];
  const float* kp = kk + (size_t)bi * T_ * C_ + c;
  const float* vp = vv + (size_t)bi * T_ * C_ + c;
  float* yp = y + (size_t)bi * T_ * C_ + c;
  float ka[8], va[8], kbu[8], vbu[8];
#pragma unroll
  for (int j = 0; j < 8; ++j) { ka[j] = kp[(size_t)j * C_]; va[j] = vp[(size_t)j * C_]; }
  for (int tc = 0; tc < T_; tc += 16) {
#pragma unroll
    for (int j = 0; j < 8; ++j) {
      const int tt = tc + 8 + j;
      kbu[j] = kp[(size_t)tt * C_]; vbu[j] = vp[(size_t)tt * C_];
    }
#pragma unroll
    for (int j = 0; j < 8; ++j) WKV_STEP(ka[j], va[j], tc + j);
#pragma unroll
    for (int j = 0; j < 8; ++j) {
      int tt = tc + 16 + j; if (tt > T_ - 1) tt = T_ - 1;
      ka[j] = kp[(size_t)tt * C_]; va[j] = vp[(size_t)tt * C_];
    }
#pragma unroll
    for (int j = 0; j < 8; ++j) WKV_STEP(kbu[j], vbu[j], tc + 8 + j);
  }
  float* ob = out_state + (size_t)bi * 3 * C_;
  ob[c] = aa; ob[C_ + c] = bbv; ob[2 * C_ + c] = pp;
}

// ---------- sigmoid(r)*y -> bf16 (r bf16, y f32) ----------
__global__ __launch_bounds__(256) void k_sry(
    const unsigned short* __restrict__ r, const float* __restrict__ y,
    unsigned short* __restrict__ sry) {
  const int nv = M_ * C_ / 8;
  for (int i = blockIdx.x * 256 + threadIdx.x; i < nv; i += gridDim.x * 256) {
    unsigned short r8[8];
    *(uint4*)r8 = ((const uint4*)r)[i];
    float4 ya = ((const float4*)y)[2 * i], yb = ((const float4*)y)[2 * i + 1];
    const float yv[8] = {ya.x, ya.y, ya.z, ya.w, yb.x, yb.y, yb.z, yb.w};
    unsigned short o8[8];
#pragma unroll
    for (int j = 0; j < 8; ++j) {
      const float s = 1.f / (1.f + expf(-b2f(r8[j])));
      o8[j] = f2bf(s * yv[j]);
    }
    ((uint4*)sry)[i] = *(uint4*)o8;
  }
}

// ---------- bf16 MFMA GEMM, 128x128 tile, BK=32, global_load_lds (m97) ----------
// A: [M][K] bf16 row-major; BT: [N][K] bf16 row-major. C[M][N] = A * BT^T.
// EPI 0: f32 store; 1: bf16(relu(acc)^2); 2: f32(aux1+acc);
// EPI 3: f32(aux1+sigmoid(acc)*aux2); 4: bf16 plain
template <int EPI>
__global__ __launch_bounds__(256, 2) void k_gemm(
    const unsigned short* __restrict__ A, const unsigned short* __restrict__ BT,
    int K, int Nn, void* __restrict__ out,
    const float* __restrict__ aux1, const float* __restrict__ aux2) {
  __shared__ unsigned short lds_a[128 * 32];
  __shared__ unsigned short lds_b[128 * 32];
  const int tid = threadIdx.x;
  const int lane = tid & 63;
  const int wv = tid >> 6;
  const int mBase = blockIdx.y * 128;
  const int nBase = blockIdx.x * 128;
  const int wr = (wv >> 1) * 64;
  const int wc = (wv & 1) * 64;
  const int r16 = lane & 15, kq = lane >> 4;
  const int srow = lane >> 2;          // row within 16-row chunk
  const int scol = (lane & 3) * 16;    // byte offset within 64B row
  const size_t strideA = (size_t)K * 2;
  f32x4 acc[4][4] = {};

  const int nk = K >> 5;
  for (int kt = 0; kt < nk; ++kt) {
    const size_t kb = (size_t)kt * 64;
#pragma unroll
    for (int i = 0; i < 2; ++i) {
      const int chunk = i * 4 + wv;
      const int row = chunk * 16 + srow;
      gload16((const char*)A + (size_t)(mBase + row) * strideA + kb + scol,
              &lds_a[chunk * 512]);
      gload16((const char*)BT + (size_t)(nBase + row) * strideA + kb + scol,
              &lds_b[chunk * 512]);
    }
    __syncthreads();
    bf16x8 af[4], bfr[4];
#pragma unroll
    for (int m = 0; m < 4; ++m)
      af[m] = *(const bf16x8*)&lds_a[(wr + m * 16 + r16) * 32 + kq * 8];
#pragma unroll
    for (int n = 0; n < 4; ++n)
      bfr[n] = *(const bf16x8*)&lds_b[(wc + n * 16 + r16) * 32 + kq * 8];
#pragma unroll
    for (int m = 0; m < 4; ++m)
#pragma unroll
      for (int n = 0; n < 4; ++n)
        acc[m][n] = __builtin_amdgcn_mfma_f32_16x16x32_bf16(af[m], bfr[n], acc[m][n], 0, 0, 0);
    __syncthreads();
  }

  const int c0 = kq * 4;
#pragma unroll
  for (int m = 0; m < 4; ++m) {
#pragma unroll
    for (int n = 0; n < 4; ++n) {
      const int col = nBase + wc + n * 16 + r16;
#pragma unroll
      for (int e = 0; e < 4; ++e) {
        const int rowg = mBase + wr + m * 16 + c0 + e;
        const size_t idx = (size_t)rowg * Nn + col;
        const float va = acc[m][n][e];
        if (EPI == 0) {
          ((float*)out)[idx] = va;
        } else if (EPI == 1) {
          const float t = va > 0.f ? va : 0.f;
          ((unsigned short*)out)[idx] = f2bf(t * t);
        } else if (EPI == 2) {
          ((float*)out)[idx] = aux1[idx] + va;
        } else if (EPI == 3) {
          const float s = 1.f / (1.f + expf(-va));
          ((float*)out)[idx] = aux1[idx] + s * aux2[idx];
        } else {
          ((unsigned short*)out)[idx] = f2bf(va);
        }
      }
    }
  }
}

extern "C" void kernel_launch(void* const* d_in, const int* in_sizes, int n_in,
                              void* d_out, int out_size, void* d_ws, size_t ws_size,
                              hipStream_t stream) {
  const float* x          = (const float*)d_in[0];
  const float* att_shift  = (const float*)d_in[1];
  const float* wkv_state  = (const float*)d_in[2];
  const float* ffn_shift  = (const float*)d_in[3];
  const float* ln1_g = (const float*)d_in[4];
  const float* ln1_b = (const float*)d_in[5];
  const float* ln2_g = (const float*)d_in[6];
  const float* ln2_b = (const float*)d_in[7];
  const float* tmk = (const float*)d_in[8];
  const float* tmv = (const float*)d_in[9];
  const float* tmr = (const float*)d_in[10];
  const float* time_decay = (const float*)d_in[11];
  const float* time_first = (const float*)d_in[12];
  const float* Wk = (const float*)d_in[13];
  const float* Wv = (const float*)d_in[14];
  const float* Wr = (const float*)d_in[15];
  const float* Wo = (const float*)d_in[16];
  const float* fmk = (const float*)d_in[17];
  const float* fmr = (const float*)d_in[18];
  const float* Fk = (const float*)d_in[19];
  const float* Fr = (const float*)d_in[20];
  const float* Fv = (const float*)d_in[21];

  // ---- 176 MiB workspace, strictly sequential reuse, zero in-flight overlap ----
  const size_t MB = 1ull << 20;
  char* ws = (char*)d_ws;
  if (ws_size < 176 * MB) return;

  unsigned short* Wslot = (unsigned short*)(ws);             //   0.. 32 weight slot
  float*          kBuf  = (float*)(ws + 32 * MB);            //  32.. 64 k f32
  float*          vBuf  = (float*)(ws + 64 * MB);            //  64.. 96 v f32
  float*          yBuf  = (float*)(ws + 96 * MB);            //  96..128 y f32 -> x_att f32
  unsigned short* h1    = (unsigned short*)(ws + 128 * MB);  // 128..144 x1 -> r -> x2
  unsigned short* h2    = (unsigned short*)(ws + 144 * MB);  // 144..160 xk -> sry -> xk2
  unsigned short* h3    = (unsigned short*)(ws + 160 * MB);  // 160..176 xv -> xr2
  unsigned short* xrT   = (unsigned short*)kBuf;             // xr bf16, before k exists
  unsigned short* kf    = (unsigned short*)kBuf;             // 64 MiB: 32..96 (k,v dead)
  float*          kv    = (float*)h1;                        // 32 MiB: 128..160 (x2,xk2 dead)

  // ---- f32 outputs, concatenated in reference return order ----
  float* outb    = (float*)d_out;
  float* x1_last = outb + (size_t)M_ * C_;        // [B,C]
  float* wkv_out = x1_last + (size_t)B_ * C_;     // [B,3,C]
  float* x2_last = wkv_out + (size_t)B_ * 3 * C_; // [B,C]

  const dim3 gCC(C_ / 32, C_ / 32);
  const dim3 gC(C_ / 128, M_ / 128);

  // ---- attention path ----
  k_layernorm<<<M_, 256, 0, stream>>>(x, ln1_g, ln1_b, h1, x1_last);           // x1 -> h1
  k_mix3<<<M_, 256, 0, stream>>>(h1, att_shift, tmk, tmv, tmr, h2, h3, xrT);   // xk,xv,xr
  k_transpose_cast<<<gCC, 256, 0, stream>>>(Wr, Wslot, C_, C_);
  k_gemm<4><<<gC, 256, 0, stream>>>(xrT, Wslot, C_, C_, h1, nullptr, nullptr); // r bf16 -> h1
  k_transpose_cast<<<gCC, 256, 0, stream>>>(Wk, Wslot, C_, C_);
  k_gemm<0><<<gC, 256, 0, stream>>>(h2, Wslot, C_, C_, kBuf, nullptr, nullptr); // k f32 (over xr, dead)
  k_transpose_cast<<<gCC, 256, 0, stream>>>(Wv, Wslot, C_, C_);
  k_gemm<0><<<gC, 256, 0, stream>>>(h3, Wslot, C_, C_, vBuf, nullptr, nullptr); // v f32
  k_wkv<<<dim3((B_ * C_) / 256), 256, 0, stream>>>(kBuf, vBuf, time_decay, time_first,
                                                   wkv_state, yBuf, wkv_out);   // y f32
  k_sry<<<1024, 256, 0, stream>>>(h1, yBuf, h2);                                // sry -> h2 (xk dead)
  k_transpose_cast<<<gCC, 256, 0, stream>>>(Wo, Wslot, C_, C_);
  k_gemm<2><<<gC, 256, 0, stream>>>(h2, Wslot, C_, C_, yBuf, x, nullptr);       // x_att f32 (over y, dead)

  // ---- ffn path ----
  k_layernorm<<<M_, 256, 0, stream>>>(yBuf, ln2_g, ln2_b, h1, x2_last);         // x2 -> h1 (r dead)
  k_mix2<<<M_, 256, 0, stream>>>(h1, ffn_shift, fmk, fmr, h2, h3);              // xk2,xr2 (sry,xv dead)
  k_transpose_cast<<<dim3(F_ / 32, C_ / 32), 256, 0, stream>>>(Fk, Wslot, C_, F_);
  k_gemm<1><<<dim3(F_ / 128, M_ / 128), 256, 0, stream>>>(h2, Wslot, C_, F_, kf,
                                                          nullptr, nullptr);    // kf bf16 (k,v dead)
  k_transpose_cast<<<dim3(C_ / 32, F_ / 32), 256, 0, stream>>>(Fv, Wslot, F_, C_);
  k_gemm<0><<<gC, 256, 0, stream>>>(kf, Wslot, F_, C_, kv, nullptr, nullptr);   // kv f32 (x2,xk2 dead)
  k_transpose_cast<<<gCC, 256, 0, stream>>>(Fr, Wslot, C_, C_);
  k_gemm<3><<<gC, 256, 0, stream>>>(h3, Wslot, C_, C_, d_out, yBuf, kv);        // final f32
}

// Round 7
// 796.916 us; speedup vs baseline: 1.3762x; 1.3762x over previous
//
#include <hip/hip_runtime.h>
#include <stdint.h>

#define B_ 2
#define T_ 2048
#define C_ 2048
#define F_ 8192
#define M_ 4096   // B_*T_
#define BC_ 4096  // B_*C_
#define CHB 16    // channels per WKV block
#define TCH 16    // time chunks per WKV block
#define LC2 128   // T_/TCH

typedef __attribute__((ext_vector_type(8))) __bf16 bf16x8;
typedef __attribute__((ext_vector_type(4))) float f32x4;

__device__ __forceinline__ unsigned short f2bf(float f) {
  union { float f; unsigned u; } v; v.f = f;
  unsigned r = v.u + 0x7fffu + ((v.u >> 16) & 1u);
  return (unsigned short)(r >> 16);
}
__device__ __forceinline__ float b2f(unsigned short h) {
  union { unsigned u; float f; } v; v.u = ((unsigned)h) << 16; return v.f;
}

__device__ __forceinline__ void gload16(const void* g, void* l) {
  __builtin_amdgcn_global_load_lds((__attribute__((address_space(1))) void*)g,
                                   (__attribute__((address_space(3))) void*)l,
                                   16, 0, 0);
}

// ---------- transpose + f32->bf16: WT[n][k] = W[k][n] ----------
__global__ __launch_bounds__(256) void k_transpose_cast(
    const float* __restrict__ W, unsigned short* __restrict__ WT, int K, int N) {
  __shared__ unsigned short tile[32][33];
  const int n0 = blockIdx.x * 32, k0 = blockIdx.y * 32;
  const int tx = threadIdx.x & 31, ty = threadIdx.x >> 5;
#pragma unroll
  for (int i = 0; i < 4; ++i)
    tile[ty + 8 * i][tx] = f2bf(W[(size_t)(k0 + ty + 8 * i) * N + n0 + tx]);
  __syncthreads();
#pragma unroll
  for (int i = 0; i < 4; ++i)
    WT[(size_t)(n0 + ty + 8 * i) * K + k0 + tx] = tile[tx][ty + 8 * i];
}

// ---------- LayerNorm over C=2048 (f32 in, bf16 out + f32 last-row out) ----------
__global__ __launch_bounds__(256) void k_layernorm(
    const float* __restrict__ x, const float* __restrict__ g,
    const float* __restrict__ beta, unsigned short* __restrict__ y,
    float* __restrict__ last_out) {
  const int row = blockIdx.x;
  const int t = row & (T_ - 1);
  const int bi = row >> 11;
  const float* xr = x + (size_t)row * C_;
  const int base = threadIdx.x * 8;
  float lv[8];
  {
    float4 a = *(const float4*)(xr + base);
    float4 b = *(const float4*)(xr + base + 4);
    lv[0]=a.x; lv[1]=a.y; lv[2]=a.z; lv[3]=a.w; lv[4]=b.x; lv[5]=b.y; lv[6]=b.z; lv[7]=b.w;
  }
  float s = 0.f, q = 0.f;
#pragma unroll
  for (int j = 0; j < 8; ++j) { s += lv[j]; q += lv[j] * lv[j]; }
#pragma unroll
  for (int o = 32; o > 0; o >>= 1) { s += __shfl_down(s, o); q += __shfl_down(q, o); }
  __shared__ float rs[4], rq[4];
  if ((threadIdx.x & 63) == 0) { rs[threadIdx.x >> 6] = s; rq[threadIdx.x >> 6] = q; }
  __syncthreads();
  s = rs[0] + rs[1] + rs[2] + rs[3];
  q = rq[0] + rq[1] + rq[2] + rq[3];
  const float mean = s * (1.f / C_);
  const float var = q * (1.f / C_) - mean * mean;
  const float inv = 1.f / sqrtf(var + 1e-5f);
  float ov[8];
  unsigned short o8[8];
#pragma unroll
  for (int j = 0; j < 8; ++j) {
    ov[j] = (lv[j] - mean) * inv * g[base + j] + beta[base + j];
    o8[j] = f2bf(ov[j]);
  }
  *(uint4*)(y + (size_t)row * C_ + base) = *(uint4*)o8;
  if (last_out != nullptr && t == T_ - 1) {
    float* lp = last_out + (size_t)bi * C_ + base;
    *(float4*)lp = make_float4(ov[0], ov[1], ov[2], ov[3]);
    *(float4*)(lp + 4) = make_float4(ov[4], ov[5], ov[6], ov[7]);
  }
}

// ---------- token-shift mix (attention: 3 outputs), bf16 in/out ----------
__global__ __launch_bounds__(256) void k_mix3(
    const unsigned short* __restrict__ x1, const float* __restrict__ shift,
    const float* __restrict__ tmk, const float* __restrict__ tmv,
    const float* __restrict__ tmr,
    unsigned short* __restrict__ xk, unsigned short* __restrict__ xv,
    unsigned short* __restrict__ xr) {
  const int row = blockIdx.x;
  const int t = row & (T_ - 1);
  const int bi = row >> 11;
  const int c0 = threadIdx.x * 8;
  const size_t o = (size_t)row * C_ + c0;
  unsigned short cur8[8];
  *(uint4*)cur8 = *(const uint4*)(x1 + o);
  float pv[8];
  if (t == 0) {
    const float* sp = shift + (size_t)bi * C_ + c0;
#pragma unroll
    for (int j = 0; j < 8; ++j) pv[j] = sp[j];
  } else {
    unsigned short p8[8];
    *(uint4*)p8 = *(const uint4*)(x1 + o - C_);
#pragma unroll
    for (int j = 0; j < 8; ++j) pv[j] = b2f(p8[j]);
  }
  unsigned short ok[8], ov[8], orr[8];
#pragma unroll
  for (int j = 0; j < 8; ++j) {
    const float a = b2f(cur8[j]), p = pv[j];
    const float mk = tmk[c0 + j], mv = tmv[c0 + j], mr = tmr[c0 + j];
    ok[j]  = f2bf(a * mk + p * (1.f - mk));
    ov[j]  = f2bf(a * mv + p * (1.f - mv));
    orr[j] = f2bf(a * mr + p * (1.f - mr));
  }
  *(uint4*)(xk + o) = *(uint4*)ok;
  *(uint4*)(xv + o) = *(uint4*)ov;
  *(uint4*)(xr + o) = *(uint4*)orr;
}

// ---------- token-shift mix (ffn: 2 outputs) ----------
__global__ __launch_bounds__(256) void k_mix2(
    const unsigned short* __restrict__ x2, const float* __restrict__ shift,
    const float* __restrict__ fmk, const float* __restrict__ fmr,
    unsigned short* __restrict__ xk2, unsigned short* __restrict__ xr2) {
  const int row = blockIdx.x;
  const int t = row & (T_ - 1);
  const int bi = row >> 11;
  const int c0 = threadIdx.x * 8;
  const size_t o = (size_t)row * C_ + c0;
  unsigned short cur8[8];
  *(uint4*)cur8 = *(const uint4*)(x2 + o);
  float pv[8];
  if (t == 0) {
    const float* sp = shift + (size_t)bi * C_ + c0;
#pragma unroll
    for (int j = 0; j < 8; ++j) pv[j] = sp[j];
  } else {
    unsigned short p8[8];
    *(uint4*)p8 = *(const uint4*)(x2 + o - C_);
#pragma unroll
    for (int j = 0; j < 8; ++j) pv[j] = b2f(p8[j]);
  }
  unsigned short ok[8], orr[8];
#pragma unroll
  for (int j = 0; j < 8; ++j) {
    const float a = b2f(cur8[j]), p = pv[j];
    const float mk = fmk[c0 + j], mr = fmr[c0 + j];
    ok[j]  = f2bf(a * mk + p * (1.f - mk));
    orr[j] = f2bf(a * mr + p * (1.f - mr));
  }
  *(uint4*)(xk2 + o) = *(uint4*)ok;
  *(uint4*)(xr2 + o) = *(uint4*)orr;
}

// ---------- WKV: single-kernel block-local chunked scan ----------
// Block = 16 channels x 16 time-chunks (L=128). Phase A: per-thread local scan
// from zero state. Phase B (LDS): 16-chunk sequential composition per channel
// into exclusive chunk-start states (chunk 0 = input state). Phase C: re-scan
// from exact start state, emit y; last chunk writes final state sequentially.
__global__ __launch_bounds__(256) void k_wkv_blk(
    const float* __restrict__ kk, const float* __restrict__ vv,
    const float* __restrict__ td, const float* __restrict__ tf,
    const float* __restrict__ st, float* __restrict__ y,
    float* __restrict__ out_state) {
  __shared__ float sA[TCH][CHB], sB[TCH][CHB], sP[TCH][CHB];
  const int blk = blockIdx.x;                 // 0..BC_/CHB-1 (=255)
  const int bi = blk >> 7;                    // C_/CHB = 128 blocks per batch
  const int tx = threadIdx.x & 15;            // channel within block
  const int ty = threadIdx.x >> 4;            // time chunk
  const int c = ((blk & 127) * CHB) + tx;
  const float w = -expf(td[c]);
  const float u = tf[c];
  const size_t base = (size_t)bi * T_ * C_ + (size_t)ty * LC2 * C_ + c;
  const float* kp = kk + base;
  const float* vp = vv + base;
  float aa = 0.f, bb = 0.f, pp = -1e38f;
#pragma unroll 8
  for (int i = 0; i < LC2; ++i) {
    const float kt = kp[(size_t)i * C_], vt = vp[(size_t)i * C_];
    const float ww2 = pp + w;
    const float p2 = fmaxf(ww2, kt);
    const float e1b = expf(ww2 - p2), e2b = expf(kt - p2);
    aa = e1b * aa + e2b * vt;
    bb = e1b * bb + e2b;
    pp = p2;
  }
  sA[ty][tx] = aa; sB[ty][tx] = bb; sP[ty][tx] = pp;
  __syncthreads();
  if (ty == 0) {
    const float* s0 = st + (size_t)bi * 3 * C_;
    float ca = s0[c], cb = s0[C_ + c], cp = s0[2 * C_ + c];
    const float wL = w * (float)LC2;
#pragma unroll
    for (int j = 0; j < TCH; ++j) {
      const float a2 = sA[j][tx], b2 = sB[j][tx], p2 = sP[j][tx];
      sA[j][tx] = ca; sB[j][tx] = cb; sP[j][tx] = cp;   // exclusive start
      const float pd = cp + wL;
      const float pm = fmaxf(pd, p2);
      const float e1 = expf(pd - pm), e2 = expf(p2 - pm);
      ca = e1 * ca + e2 * a2;
      cb = e1 * cb + e2 * b2;
      cp = pm;
    }
  }
  __syncthreads();
  aa = sA[ty][tx]; bb = sB[ty][tx]; pp = sP[ty][tx];
  float* yp = y + base;
#pragma unroll 4
  for (int i = 0; i < LC2; ++i) {
    const float kt = kp[(size_t)i * C_], vt = vp[(size_t)i * C_];
    const float ww = u + kt;
    const float p = fmaxf(pp, ww);
    const float e1 = expf(pp - p), e2 = expf(ww - p);
    yp[(size_t)i * C_] = (e1 * aa + e2 * vt) / (e1 * bb + e2);
    const float ww2 = pp + w;
    const float p2 = fmaxf(ww2, kt);
    const float e1b = expf(ww2 - p2), e2b = expf(kt - p2);
    aa = e1b * aa + e2b * vt;
    bb = e1b * bb + e2b;
    pp = p2;
  }
  if (ty == TCH - 1) {
    float* ob = out_state + (size_t)bi * 3 * C_;
    ob[c] = aa; ob[C_ + c] = bb; ob[2 * C_ + c] = pp;
  }
}

// ---------- sigmoid(r)*y -> bf16 (r bf16, y f32) ----------
__global__ __launch_bounds__(256) void k_sry(
    const unsigned short* __restrict__ r, const float* __restrict__ y,
    unsigned short* __restrict__ sry) {
  const int nv = M_ * C_ / 8;
  for (int i = blockIdx.x * 256 + threadIdx.x; i < nv; i += gridDim.x * 256) {
    unsigned short r8[8];
    *(uint4*)r8 = ((const uint4*)r)[i];
    float4 ya = ((const float4*)y)[2 * i], yb = ((const float4*)y)[2 * i + 1];
    const float yv[8] = {ya.x, ya.y, ya.z, ya.w, yb.x, yb.y, yb.z, yb.w};
    unsigned short o8[8];
#pragma unroll
    for (int j = 0; j < 8; ++j) {
      const float s = 1.f / (1.f + expf(-b2f(r8[j])));
      o8[j] = f2bf(s * yv[j]);
    }
    ((uint4*)sry)[i] = *(uint4*)o8;
  }
}

// ---------- bf16 MFMA GEMM, 128x128 tile, BK=32, global_load_lds (m97) ----------
// A: [M][K] bf16 row-major; BT: [N][K] bf16 row-major. C[M][N] = A * BT^T.
// EPI 0: f32 store; 1: bf16(relu(acc)^2); 2: f32(aux1+acc);
// EPI 3: f32(aux1+sigmoid(acc)*aux2); 4: bf16 plain
template <int EPI>
__global__ __launch_bounds__(256, 2) void k_gemm(
    const unsigned short* __restrict__ A, const unsigned short* __restrict__ BT,
    int K, int Nn, void* __restrict__ out,
    const float* __restrict__ aux1, const float* __restrict__ aux2) {
  __shared__ unsigned short lds_a[128 * 32];
  __shared__ unsigned short lds_b[128 * 32];
  const int tid = threadIdx.x;
  const int lane = tid & 63;
  const int wv = tid >> 6;
  const int mBase = blockIdx.y * 128;
  const int nBase = blockIdx.x * 128;
  const int wr = (wv >> 1) * 64;
  const int wc = (wv & 1) * 64;
  const int r16 = lane & 15, kq = lane >> 4;
  const int srow = lane >> 2;          // row within 16-row chunk
  const int scol = (lane & 3) * 16;    // byte offset within 64B row
  const size_t strideA = (size_t)K * 2;
  f32x4 acc[4][4] = {};

  const int nk = K >> 5;
  for (int kt = 0; kt < nk; ++kt) {
    const size_t kb = (size_t)kt * 64;
#pragma unroll
    for (int i = 0; i < 2; ++i) {
      const int chunk = i * 4 + wv;
      const int row = chunk * 16 + srow;
      gload16((const char*)A + (size_t)(mBase + row) * strideA + kb + scol,
              &lds_a[chunk * 512]);
      gload16((const char*)BT + (size_t)(nBase + row) * strideA + kb + scol,
              &lds_b[chunk * 512]);
    }
    __syncthreads();
    bf16x8 af[4], bfr[4];
#pragma unroll
    for (int m = 0; m < 4; ++m)
      af[m] = *(const bf16x8*)&lds_a[(wr + m * 16 + r16) * 32 + kq * 8];
#pragma unroll
    for (int n = 0; n < 4; ++n)
      bfr[n] = *(const bf16x8*)&lds_b[(wc + n * 16 + r16) * 32 + kq * 8];
#pragma unroll
    for (int m = 0; m < 4; ++m)
#pragma unroll
      for (int n = 0; n < 4; ++n)
        acc[m][n] = __builtin_amdgcn_mfma_f32_16x16x32_bf16(af[m], bfr[n], acc[m][n], 0, 0, 0);
    __syncthreads();
  }

  const int c0 = kq * 4;
#pragma unroll
  for (int m = 0; m < 4; ++m) {
#pragma unroll
    for (int n = 0; n < 4; ++n) {
      const int col = nBase + wc + n * 16 + r16;
#pragma unroll
      for (int e = 0; e < 4; ++e) {
        const int rowg = mBase + wr + m * 16 + c0 + e;
        const size_t idx = (size_t)rowg * Nn + col;
        const float va = acc[m][n][e];
        if (EPI == 0) {
          ((float*)out)[idx] = va;
        } else if (EPI == 1) {
          const float t = va > 0.f ? va : 0.f;
          ((unsigned short*)out)[idx] = f2bf(t * t);
        } else if (EPI == 2) {
          ((float*)out)[idx] = aux1[idx] + va;
        } else if (EPI == 3) {
          const float s = 1.f / (1.f + expf(-va));
          ((float*)out)[idx] = aux1[idx] + s * aux2[idx];
        } else {
          ((unsigned short*)out)[idx] = f2bf(va);
        }
      }
    }
  }
}

extern "C" void kernel_launch(void* const* d_in, const int* in_sizes, int n_in,
                              void* d_out, int out_size, void* d_ws, size_t ws_size,
                              hipStream_t stream) {
  const float* x          = (const float*)d_in[0];
  const float* att_shift  = (const float*)d_in[1];
  const float* wkv_state  = (const float*)d_in[2];
  const float* ffn_shift  = (const float*)d_in[3];
  const float* ln1_g = (const float*)d_in[4];
  const float* ln1_b = (const float*)d_in[5];
  const float* ln2_g = (const float*)d_in[6];
  const float* ln2_b = (const float*)d_in[7];
  const float* tmk = (const float*)d_in[8];
  const float* tmv = (const float*)d_in[9];
  const float* tmr = (const float*)d_in[10];
  const float* time_decay = (const float*)d_in[11];
  const float* time_first = (const float*)d_in[12];
  const float* Wk = (const float*)d_in[13];
  const float* Wv = (const float*)d_in[14];
  const float* Wr = (const float*)d_in[15];
  const float* Wo = (const float*)d_in[16];
  const float* fmk = (const float*)d_in[17];
  const float* fmr = (const float*)d_in[18];
  const float* Fk = (const float*)d_in[19];
  const float* Fr = (const float*)d_in[20];
  const float* Fv = (const float*)d_in[21];

  // ---- 176 MiB workspace, strictly sequential reuse, zero in-flight overlap ----
  const size_t MB = 1ull << 20;
  char* ws = (char*)d_ws;
  if (ws_size < 176 * MB) return;

  unsigned short* Wslot = (unsigned short*)(ws);             //   0.. 32 weight slot
  float*          kBuf  = (float*)(ws + 32 * MB);            //  32.. 64 k f32
  float*          vBuf  = (float*)(ws + 64 * MB);            //  64.. 96 v f32
  float*          yBuf  = (float*)(ws + 96 * MB);            //  96..128 y f32 -> x_att f32
  unsigned short* h1    = (unsigned short*)(ws + 128 * MB);  // 128..144 x1 -> r -> x2
  unsigned short* h2    = (unsigned short*)(ws + 144 * MB);  // 144..160 xk -> sry -> xk2
  unsigned short* h3    = (unsigned short*)(ws + 160 * MB);  // 160..176 xv -> xr2
  unsigned short* xrT   = (unsigned short*)kBuf;             // xr bf16, before k exists
  unsigned short* kf    = (unsigned short*)kBuf;             // 64 MiB: 32..96 (k,v dead)
  float*          kv    = (float*)h1;                        // 32 MiB: 128..160 (x2,xk2 dead)

  // ---- f32 outputs, concatenated in reference return order ----
  float* outb    = (float*)d_out;
  float* x1_last = outb + (size_t)M_ * C_;        // [B,C]
  float* wkv_out = x1_last + (size_t)B_ * C_;     // [B,3,C]
  float* x2_last = wkv_out + (size_t)B_ * 3 * C_; // [B,C]

  const dim3 gCC(C_ / 32, C_ / 32);
  const dim3 gC(C_ / 128, M_ / 128);

  // ---- attention path ----
  k_layernorm<<<M_, 256, 0, stream>>>(x, ln1_g, ln1_b, h1, x1_last);           // x1 -> h1
  k_mix3<<<M_, 256, 0, stream>>>(h1, att_shift, tmk, tmv, tmr, h2, h3, xrT);   // xk,xv,xr
  k_transpose_cast<<<gCC, 256, 0, stream>>>(Wr, Wslot, C_, C_);
  k_gemm<4><<<gC, 256, 0, stream>>>(xrT, Wslot, C_, C_, h1, nullptr, nullptr); // r bf16 -> h1
  k_transpose_cast<<<gCC, 256, 0, stream>>>(Wk, Wslot, C_, C_);
  k_gemm<0><<<gC, 256, 0, stream>>>(h2, Wslot, C_, C_, kBuf, nullptr, nullptr); // k f32 (over xr, dead)
  k_transpose_cast<<<gCC, 256, 0, stream>>>(Wv, Wslot, C_, C_);
  k_gemm<0><<<gC, 256, 0, stream>>>(h3, Wslot, C_, C_, vBuf, nullptr, nullptr); // v f32
  // WKV: single kernel, block-local scan (no cross-kernel scratch)
  k_wkv_blk<<<dim3(BC_ / CHB), 256, 0, stream>>>(kBuf, vBuf, time_decay, time_first,
                                                 wkv_state, yBuf, wkv_out);
  k_sry<<<1024, 256, 0, stream>>>(h1, yBuf, h2);                                // sry -> h2 (xk dead)
  k_transpose_cast<<<gCC, 256, 0, stream>>>(Wo, Wslot, C_, C_);
  k_gemm<2><<<gC, 256, 0, stream>>>(h2, Wslot, C_, C_, yBuf, x, nullptr);       // x_att f32 (over y, dead)

  // ---- ffn path ----
  k_layernorm<<<M_, 256, 0, stream>>>(yBuf, ln2_g, ln2_b, h1, x2_last);         // x2 -> h1 (r dead)
  k_mix2<<<M_, 256, 0, stream>>>(h1, ffn_shift, fmk, fmr, h2, h3);              // xk2,xr2 (sry,xv dead)
  k_transpose_cast<<<dim3(F_ / 32, C_ / 32), 256, 0, stream>>>(Fk, Wslot, C_, F_);
  k_gemm<1><<<dim3(F_ / 128, M_ / 128), 256, 0, stream>>>(h2, Wslot, C_, F_, kf,
                                                          nullptr, nullptr);    // kf bf16 (k,v dead)
  k_transpose_cast<<<dim3(C_ / 32, F_ / 32), 256, 0, stream>>>(Fv, Wslot, F_, C_);
  k_gemm<0><<<gC, 256, 0, stream>>>(kf, Wslot, F_, C_, kv, nullptr, nullptr);   // kv f32 (x2,xk2 dead)
  k_transpose_cast<<<gCC, 256, 0, stream>>>(Fr, Wslot, C_, C_);
  k_gemm<3><<<gC, 256, 0, stream>>>(h3, Wslot, C_, C_, d_out, yBuf, kv);        // final f32
}